// Round 1
// baseline (4287.094 us; speedup 1.0000x reference)
//
#include <hip/hip_runtime.h>
#include <cstdint>
#include <cstddef>

// ---------------------------------------------------------------------------
// GCN encoder: 2x (GEMM -> gather/scatter aggregate -> bias[+ReLU])
// out[v] = dinv[v] * sum_{e: dst=v} dinv[src]*h[src] + dinv[v]^2 * h[v] + b
// ---------------------------------------------------------------------------

static constexpr int CH1 = 256;
static constexpr int CH2 = 128;

__global__ void k_set_int(int* p, int v) { *p = v; }

__global__ void k_fill1(float* __restrict__ p, int n) {
  int i = blockIdx.x * blockDim.x + threadIdx.x;
  if (i < n) p[i] = 1.0f;
}

__global__ void k_zero4(float4* __restrict__ p, int n4) {
  int i = blockIdx.x * blockDim.x + threadIdx.x;
  if (i < n4) p[i] = make_float4(0.f, 0.f, 0.f, 0.f);
}

// Detect whether the edge buffer is int32 or int64.
// If int64 (little-endian, values < 50000), every odd 32-bit word of the first
// 2*E words is 0. If int32, odd words are random indices (some nonzero).
// flag=1 -> int32 layout, flag=0 -> int64 layout.
__global__ void k_detect_i32(const unsigned int* __restrict__ w, int nwords,
                             int* __restrict__ flag) {
  int i = blockIdx.x * blockDim.x + threadIdx.x;
  if (i < nwords && (i & 1) && w[i] != 0u) *flag = 1;
}

__global__ void k_cvt_edges(const void* __restrict__ raw, int* __restrict__ e32,
                            int n, const int* __restrict__ flag) {
  int i = blockIdx.x * blockDim.x + threadIdx.x;
  if (i >= n) return;
  if (*flag) e32[i] = ((const int*)raw)[i];
  else       e32[i] = (int)((const long long*)raw)[i];
}

__global__ void k_degcount(const int* __restrict__ dst, float* __restrict__ deg, int E) {
  int e = blockIdx.x * blockDim.x + threadIdx.x;
  if (e < E) atomicAdd(&deg[dst[e]], 1.0f);
}

__global__ void k_dinv(float* __restrict__ deg, int n) {
  int i = blockIdx.x * blockDim.x + threadIdx.x;
  if (i < n) deg[i] = 1.0f / sqrtf(deg[i]);  // deg >= 1 (self-loop)
}

// ---------------------------------------------------------------------------
// fp32 tiled GEMM: C[M,N] = A[M,K] @ B[K,N], row-major. BM=BN=64, BK=16,
// 256 threads, 4x4 microtile per thread. (No fp32 MFMA on CDNA4.)
// ---------------------------------------------------------------------------
template <int BM, int BN, int BK>
__global__ __launch_bounds__(256) void k_gemm_f32(
    const float* __restrict__ A, const float* __restrict__ B,
    float* __restrict__ C, int M, int N, int K) {
  __shared__ float As[BK][BM + 4];  // +4 pad: keeps 16B alignment, breaks conflicts
  __shared__ float Bs[BK][BN + 4];
  const int t = threadIdx.x;
  const int m0 = blockIdx.x * BM;
  const int n0 = blockIdx.y * BN;
  const int tx = t & 15, ty = t >> 4;
  float acc[4][4] = {};
  for (int k0 = 0; k0 < K; k0 += BK) {
    {
      int row = t >> 2;          // 0..63
      int kk  = (t & 3) * 4;     // 0,4,8,12
      int gm  = m0 + row;
      float4 v = make_float4(0.f, 0.f, 0.f, 0.f);
      if (gm < M) v = *(const float4*)(A + (size_t)gm * K + k0 + kk);
      As[kk + 0][row] = v.x; As[kk + 1][row] = v.y;
      As[kk + 2][row] = v.z; As[kk + 3][row] = v.w;
    }
    {
      int kk = t >> 4;           // 0..15
      int nn = (t & 15) * 4;     // 0..60
      float4 v = *(const float4*)(B + (size_t)(k0 + kk) * N + n0 + nn);
      *(float4*)&Bs[kk][nn] = v;
    }
    __syncthreads();
#pragma unroll
    for (int k = 0; k < BK; ++k) {
      float4 a = *(const float4*)&As[k][ty * 4];
      float4 b = *(const float4*)&Bs[k][tx * 4];
      float av[4] = {a.x, a.y, a.z, a.w};
      float bv[4] = {b.x, b.y, b.z, b.w};
#pragma unroll
      for (int i = 0; i < 4; ++i)
#pragma unroll
        for (int j = 0; j < 4; ++j) acc[i][j] += av[i] * bv[j];
    }
    __syncthreads();
  }
#pragma unroll
  for (int i = 0; i < 4; ++i) {
    int gm = m0 + ty * 4 + i;
    if (gm < M) {
      float4 v = make_float4(acc[i][0], acc[i][1], acc[i][2], acc[i][3]);
      *(float4*)(C + (size_t)gm * N + n0 + tx * 4) = v;
    }
  }
}

// ---------------------------------------------------------------------------
// Edge scatter: agg[dst] += dinv[src] * h[src]   (dinv[dst] applied later)
// One thread handles 4 channels of one edge.
// ---------------------------------------------------------------------------
template <int C>
__global__ __launch_bounds__(256) void k_scatter(
    const int* __restrict__ src, const int* __restrict__ dst,
    const float* __restrict__ dinv, const float* __restrict__ h,
    float* __restrict__ agg, int E) {
  constexpr int PER = C / 4;
  long long idx = (long long)blockIdx.x * 256 + threadIdx.x;
  long long e = idx / PER;
  if (e >= E) return;
  int c4 = (int)(idx - e * PER) * 4;
  int s = src[e], d = dst[e];
  float w = dinv[s];
  float4 v = *(const float4*)(h + (size_t)s * C + c4);
  float* p = agg + (size_t)d * C + c4;
  atomicAdd(p + 0, v.x * w);
  atomicAdd(p + 1, v.y * w);
  atomicAdd(p + 2, v.z * w);
  atomicAdd(p + 3, v.w * w);
}

// out[v,c] = (relu?)( dinv[v]*agg[v,c] + dinv[v]^2*h[v,c] + b[c] )
template <int C, bool RELU>
__global__ __launch_bounds__(256) void k_finalize(
    const float* __restrict__ agg, const float* __restrict__ h,
    const float* __restrict__ dinv, const float* __restrict__ bias,
    float* __restrict__ out, int n4) {
  constexpr int C4 = C / 4;
  int i = blockIdx.x * blockDim.x + threadIdx.x;  // one float4 per thread
  if (i >= n4) return;
  int v  = i / C4;
  int c4 = (i - v * C4) * 4;
  float di = dinv[v];
  float di2 = di * di;
  float4 a = *(const float4*)(agg + (size_t)i * 4);
  float4 hh = *(const float4*)(h + (size_t)i * 4);
  float4 b = *(const float4*)(bias + c4);
  float4 o;
  o.x = di * a.x + di2 * hh.x + b.x;
  o.y = di * a.y + di2 * hh.y + b.y;
  o.z = di * a.z + di2 * hh.z + b.z;
  o.w = di * a.w + di2 * hh.w + b.w;
  if (RELU) {
    o.x = fmaxf(o.x, 0.f); o.y = fmaxf(o.y, 0.f);
    o.z = fmaxf(o.z, 0.f); o.w = fmaxf(o.w, 0.f);
  }
  *(float4*)(out + (size_t)i * 4) = o;
}

// ---------------------------------------------------------------------------

extern "C" void kernel_launch(void* const* d_in, const int* in_sizes, int n_in,
                              void* d_out, int out_size, void* d_ws, size_t ws_size,
                              hipStream_t stream) {
  const float* x  = (const float*)d_in[0];
  const void*  ei = d_in[1];
  const float* W1 = (const float*)d_in[2];
  const float* b1 = (const float*)d_in[3];
  const float* W2 = (const float*)d_in[4];
  const float* b2 = (const float*)d_in[5];
  float* out = (float*)d_out;

  const int N = in_sizes[0] / CH1;  // 50000
  const int E = in_sizes[1] / 2;    // 800000

  char* w = (char*)d_ws;
  size_t off = 0;
  auto alloc = [&](size_t bytes) -> void* {
    void* p = w + off;
    off += (bytes + 255) & ~(size_t)255;
    return p;
  };
  float* deg  = (float*)alloc((size_t)N * 4);             // becomes dinv
  int*   flag = (int*)alloc(256);
  int*   e32  = (int*)alloc((size_t)2 * E * 4);
  float* bufA = (float*)alloc((size_t)N * CH1 * 4);
  float* bufB = (float*)alloc((size_t)N * CH1 * 4);

  const int* srcI = e32;
  const int* dstI = e32 + E;

  dim3 blk(256);
  auto cdiv = [](long long a, long long b) { return (int)((a + b - 1) / b); };

  // --- edge preprocessing -------------------------------------------------
  k_set_int<<<1, 1, 0, stream>>>(flag, 0);
  k_detect_i32<<<cdiv(2LL * E, 256), blk, 0, stream>>>((const unsigned int*)ei, 2 * E, flag);
  k_cvt_edges<<<cdiv(2LL * E, 256), blk, 0, stream>>>(ei, e32, 2 * E, flag);
  k_fill1<<<cdiv(N, 256), blk, 0, stream>>>(deg, N);
  k_degcount<<<cdiv(E, 256), blk, 0, stream>>>(dstI, deg, E);
  k_dinv<<<cdiv(N, 256), blk, 0, stream>>>(deg, N);

  // --- layer 1: h1 = x@W1 ; agg ; relu(dinv*agg + dinv^2*h1 + b1) ---------
  dim3 g1(cdiv(N, 64), CH1 / 64);
  k_gemm_f32<64, 64, 16><<<g1, blk, 0, stream>>>(x, W1, bufA, N, CH1, CH1);
  k_zero4<<<cdiv((long long)N * CH1 / 4, 256), blk, 0, stream>>>((float4*)bufB, N * CH1 / 4);
  k_scatter<CH1><<<cdiv((long long)E * (CH1 / 4), 256), blk, 0, stream>>>(srcI, dstI, deg, bufA, bufB, E);
  k_finalize<CH1, true><<<cdiv((long long)N * CH1 / 4, 256), blk, 0, stream>>>(bufB, bufA, deg, b1, bufA, N * CH1 / 4);

  // --- layer 2: h2 = f1@W2 ; agg ; dinv*agg + dinv^2*h2 + b2 -> out -------
  dim3 g2(cdiv(N, 64), CH2 / 64);
  k_gemm_f32<64, 64, 16><<<g2, blk, 0, stream>>>(bufA, W2, bufB, N, CH2, CH1);
  k_zero4<<<cdiv((long long)N * CH2 / 4, 256), blk, 0, stream>>>((float4*)bufA, N * CH2 / 4);
  k_scatter<CH2><<<cdiv((long long)E * (CH2 / 4), 256), blk, 0, stream>>>(srcI, dstI, deg, bufB, bufA, E);
  k_finalize<CH2, false><<<cdiv((long long)N * CH2 / 4, 256), blk, 0, stream>>>(bufA, bufB, deg, b2, out, N * CH2 / 4);
}

// Round 3
// 432.165 us; speedup vs baseline: 9.9200x; 9.9200x over previous
//
#include <hip/hip_runtime.h>
#include <cstdint>
#include <cstddef>

// ---------------------------------------------------------------------------
// GCN encoder, CSR formulation:
//   out[v] = dinv[v] * sum_{e:dst=v} dinv[src]*h[src] + dinv[v]^2*h[v] + b
// CSR (edges grouped by dst) built on-device each call; aggregation is a
// per-node gather-reduce (no float atomics), fused with bias/ReLU epilogue.
// ---------------------------------------------------------------------------

static constexpr int CH1 = 256;
static constexpr int CH2 = 128;

__global__ void k_set_int(int* p, int v) { *p = v; }

__global__ void k_zero_int(int* __restrict__ p, int n) {
  int i = blockIdx.x * blockDim.x + threadIdx.x;
  if (i < n) p[i] = 0;
}

// Detect int32 vs int64 edge buffer: for int64 little-endian values <50000,
// every odd 32-bit word is 0. flag=1 -> int32 layout.
__global__ void k_detect_i32(const unsigned int* __restrict__ w, int nwords,
                             int* __restrict__ flag) {
  int i = blockIdx.x * blockDim.x + threadIdx.x;
  if (i < nwords && (i & 1) && w[i] != 0u) *flag = 1;
}

__global__ void k_cvt_edges(const void* __restrict__ raw, int* __restrict__ e32,
                            int n, const int* __restrict__ flag) {
  int i = blockIdx.x * blockDim.x + threadIdx.x;
  if (i >= n) return;
  if (*flag) e32[i] = ((const int*)raw)[i];
  else       e32[i] = (int)((const long long*)raw)[i];
}

__global__ void k_degcount(const int* __restrict__ dst, int* __restrict__ deg, int E) {
  int e = blockIdx.x * blockDim.x + threadIdx.x;
  if (e < E) atomicAdd(&deg[dst[e]], 1);
}

// ---- 3-kernel exclusive scan of deg[N] -> rowstart[N+1] -------------------
__global__ __launch_bounds__(256) void k_chunk_sum(const int* __restrict__ deg,
                                                   int* __restrict__ bsum, int N) {
  __shared__ int sh[256];
  int i = blockIdx.x * 256 + threadIdx.x;
  sh[threadIdx.x] = (i < N) ? deg[i] : 0;
  __syncthreads();
  for (int off = 128; off > 0; off >>= 1) {
    if (threadIdx.x < (unsigned)off) sh[threadIdx.x] += sh[threadIdx.x + off];
    __syncthreads();
  }
  if (threadIdx.x == 0) bsum[blockIdx.x] = sh[0];
}

__global__ __launch_bounds__(256) void k_scan_bsums(int* __restrict__ bsum, int nb) {
  __shared__ int sh[256];
  int t = threadIdx.x;
  int v = (t < nb) ? bsum[t] : 0;
  sh[t] = v;
  __syncthreads();
  for (int off = 1; off < 256; off <<= 1) {
    int add = (t >= off) ? sh[t - off] : 0;
    __syncthreads();
    sh[t] += add;
    __syncthreads();
  }
  if (t < nb) bsum[t] = sh[t] - v;  // exclusive
}

__global__ __launch_bounds__(256) void k_chunk_scan(
    const int* __restrict__ deg, const int* __restrict__ bsum,
    int* __restrict__ rowstart, int* __restrict__ cursor,
    float* __restrict__ dinv, int N, int E) {
  __shared__ int sh[256];
  int t = threadIdx.x;
  int i = blockIdx.x * 256 + t;
  int d = (i < N) ? deg[i] : 0;
  sh[t] = d;
  __syncthreads();
  for (int off = 1; off < 256; off <<= 1) {
    int add = (t >= off) ? sh[t - off] : 0;
    __syncthreads();
    sh[t] += add;
    __syncthreads();
  }
  if (i < N) {
    int rs = bsum[blockIdx.x] + sh[t] - d;
    rowstart[i] = rs;
    cursor[i]   = rs;
    dinv[i] = rsqrtf((float)(d + 1));  // +1: self-loop
  }
  if (i == 0) rowstart[N] = E;
}

__global__ void k_fill(const int* __restrict__ src, const int* __restrict__ dst,
                       int* __restrict__ cursor, int* __restrict__ csr, int E) {
  int e = blockIdx.x * blockDim.x + threadIdx.x;
  if (e < E) {
    int pos = atomicAdd(&cursor[dst[e]], 1);
    csr[pos] = src[e];
  }
}

// ---------------------------------------------------------------------------
// fp32 tiled GEMM: C[M,N] = A[M,K] @ B[K,N], row-major. BM=BN=64, BK=16.
// ---------------------------------------------------------------------------
template <int BM, int BN, int BK>
__global__ __launch_bounds__(256) void k_gemm_f32(
    const float* __restrict__ A, const float* __restrict__ B,
    float* __restrict__ C, int M, int N, int K) {
  __shared__ float As[BK][BM + 4];
  __shared__ float Bs[BK][BN + 4];
  const int t = threadIdx.x;
  const int m0 = blockIdx.x * BM;
  const int n0 = blockIdx.y * BN;
  const int tx = t & 15, ty = t >> 4;
  float acc[4][4] = {};
  for (int k0 = 0; k0 < K; k0 += BK) {
    {
      int row = t >> 2;
      int kk  = (t & 3) * 4;
      int gm  = m0 + row;
      float4 v = make_float4(0.f, 0.f, 0.f, 0.f);
      if (gm < M) v = *(const float4*)(A + (size_t)gm * K + k0 + kk);
      As[kk + 0][row] = v.x; As[kk + 1][row] = v.y;
      As[kk + 2][row] = v.z; As[kk + 3][row] = v.w;
    }
    {
      int kk = t >> 4;
      int nn = (t & 15) * 4;
      float4 v = *(const float4*)(B + (size_t)(k0 + kk) * N + n0 + nn);
      *(float4*)&Bs[kk][nn] = v;
    }
    __syncthreads();
#pragma unroll
    for (int k = 0; k < BK; ++k) {
      float4 a = *(const float4*)&As[k][ty * 4];
      float4 b = *(const float4*)&Bs[k][tx * 4];
      float av[4] = {a.x, a.y, a.z, a.w};
      float bv[4] = {b.x, b.y, b.z, b.w};
#pragma unroll
      for (int i = 0; i < 4; ++i)
#pragma unroll
        for (int j = 0; j < 4; ++j) acc[i][j] += av[i] * bv[j];
    }
    __syncthreads();
  }
#pragma unroll
  for (int i = 0; i < 4; ++i) {
    int gm = m0 + ty * 4 + i;
    if (gm < M) {
      float4 v = make_float4(acc[i][0], acc[i][1], acc[i][2], acc[i][3]);
      *(float4*)(C + (size_t)gm * N + n0 + tx * 4) = v;
    }
  }
}

// ---------------------------------------------------------------------------
// Per-node gather-reduce + fused epilogue. One 64-lane wave per node.
// C=256 -> float4/lane, C=128 -> float2/lane. 4-edge unroll for MLP.
// ---------------------------------------------------------------------------
template <int C, bool RELU>
__global__ __launch_bounds__(256) void k_aggregate(
    const int* __restrict__ rowstart, const int* __restrict__ csr,
    const float* __restrict__ dinv, const float* __restrict__ h,
    const float* __restrict__ bias, float* __restrict__ out, int N) {
  constexpr int V = C / 64;
  static_assert(V == 2 || V == 4, "C must be 128 or 256");
  int wv = blockIdx.x * 4 + (threadIdx.x >> 6);
  if (wv >= N) return;
  int lane = threadIdx.x & 63;
  int c0 = lane * V;
  int beg = rowstart[wv], end = rowstart[wv + 1];
  float acc[V] = {};
  int j = beg;
  for (; j + 4 <= end; j += 4) {
    int s0 = csr[j], s1 = csr[j + 1], s2 = csr[j + 2], s3 = csr[j + 3];
    float w0 = dinv[s0], w1 = dinv[s1], w2 = dinv[s2], w3 = dinv[s3];
    const float* p0 = h + (size_t)s0 * C + c0;
    const float* p1 = h + (size_t)s1 * C + c0;
    const float* p2 = h + (size_t)s2 * C + c0;
    const float* p3 = h + (size_t)s3 * C + c0;
    if constexpr (V == 4) {
      float4 a0 = *(const float4*)p0, a1 = *(const float4*)p1;
      float4 a2 = *(const float4*)p2, a3 = *(const float4*)p3;
      acc[0] += w0 * a0.x + w1 * a1.x + w2 * a2.x + w3 * a3.x;
      acc[1] += w0 * a0.y + w1 * a1.y + w2 * a2.y + w3 * a3.y;
      acc[2] += w0 * a0.z + w1 * a1.z + w2 * a2.z + w3 * a3.z;
      acc[3] += w0 * a0.w + w1 * a1.w + w2 * a2.w + w3 * a3.w;
    } else {
      float2 a0 = *(const float2*)p0, a1 = *(const float2*)p1;
      float2 a2 = *(const float2*)p2, a3 = *(const float2*)p3;
      acc[0] += w0 * a0.x + w1 * a1.x + w2 * a2.x + w3 * a3.x;
      acc[1] += w0 * a0.y + w1 * a1.y + w2 * a2.y + w3 * a3.y;
    }
  }
  for (; j < end; ++j) {
    int s = csr[j];
    float ws = dinv[s];
    const float* p = h + (size_t)s * C + c0;
    if constexpr (V == 4) {
      float4 a = *(const float4*)p;
      acc[0] += ws * a.x; acc[1] += ws * a.y;
      acc[2] += ws * a.z; acc[3] += ws * a.w;
    } else {
      float2 a = *(const float2*)p;
      acc[0] += ws * a.x; acc[1] += ws * a.y;
    }
  }
  float dv = dinv[wv];
  float sw = dv * dv;
  const float* hp = h + (size_t)wv * C + c0;
  const float* bp = bias + c0;
  float* op = out + (size_t)wv * C + c0;
  if constexpr (V == 4) {
    float4 hh = *(const float4*)hp;
    float4 bb = *(const float4*)bp;
    float4 o;
    o.x = dv * acc[0] + sw * hh.x + bb.x;
    o.y = dv * acc[1] + sw * hh.y + bb.y;
    o.z = dv * acc[2] + sw * hh.z + bb.z;
    o.w = dv * acc[3] + sw * hh.w + bb.w;
    if (RELU) {
      o.x = fmaxf(o.x, 0.f); o.y = fmaxf(o.y, 0.f);
      o.z = fmaxf(o.z, 0.f); o.w = fmaxf(o.w, 0.f);
    }
    *(float4*)op = o;
  } else {
    float2 hh = *(const float2*)hp;
    float2 bb = *(const float2*)bp;
    float2 o;
    o.x = dv * acc[0] + sw * hh.x + bb.x;
    o.y = dv * acc[1] + sw * hh.y + bb.y;
    if (RELU) { o.x = fmaxf(o.x, 0.f); o.y = fmaxf(o.y, 0.f); }
    *(float2*)op = o;
  }
}

// ---------------------------------------------------------------------------

extern "C" void kernel_launch(void* const* d_in, const int* in_sizes, int n_in,
                              void* d_out, int out_size, void* d_ws, size_t ws_size,
                              hipStream_t stream) {
  const float* x  = (const float*)d_in[0];
  const void*  ei = d_in[1];
  const float* W1 = (const float*)d_in[2];
  const float* b1 = (const float*)d_in[3];
  const float* W2 = (const float*)d_in[4];
  const float* b2 = (const float*)d_in[5];
  float* out = (float*)d_out;

  const int N = in_sizes[0] / CH1;  // 50000
  const int E = in_sizes[1] / 2;    // 800000

  char* w = (char*)d_ws;
  size_t off = 0;
  auto alloc = [&](size_t bytes) -> void* {
    void* p = w + off;
    off += (bytes + 255) & ~(size_t)255;
    return p;
  };
  int*   deg      = (int*)alloc((size_t)N * 4);
  int*   flag     = (int*)alloc(256);
  int*   e32      = (int*)alloc((size_t)2 * E * 4);
  int*   rowstart = (int*)alloc((size_t)(N + 1) * 4);
  int*   cursor   = (int*)alloc((size_t)N * 4);
  int*   bsum     = (int*)alloc(256 * 4);
  int*   csr      = (int*)alloc((size_t)E * 4);
  float* dinv     = (float*)alloc((size_t)N * 4);
  float* bufA     = (float*)alloc((size_t)N * CH1 * 4);
  float* bufB     = (float*)alloc((size_t)N * CH1 * 4);

  const int* srcI = e32;
  const int* dstI = e32 + E;

  dim3 blk(256);
  auto cdiv = [](long long a, long long b) { return (int)((a + b - 1) / b); };
  const int nchunks = cdiv(N, 256);  // 196

  // --- edge preprocessing + CSR build ------------------------------------
  k_set_int<<<1, 1, 0, stream>>>(flag, 0);
  k_detect_i32<<<cdiv(2LL * E, 256), blk, 0, stream>>>((const unsigned int*)ei, 2 * E, flag);
  k_cvt_edges<<<cdiv(2LL * E, 256), blk, 0, stream>>>(ei, e32, 2 * E, flag);
  k_zero_int<<<cdiv(N, 256), blk, 0, stream>>>(deg, N);
  k_degcount<<<cdiv(E, 256), blk, 0, stream>>>(dstI, deg, E);
  k_chunk_sum<<<nchunks, blk, 0, stream>>>(deg, bsum, N);
  k_scan_bsums<<<1, blk, 0, stream>>>(bsum, nchunks);
  k_chunk_scan<<<nchunks, blk, 0, stream>>>(deg, bsum, rowstart, cursor, dinv, N, E);
  k_fill<<<cdiv(E, 256), blk, 0, stream>>>(srcI, dstI, cursor, csr, E);

  // --- layer 1: h1 = x@W1 ; fused aggregate+bias+relu -> bufB -------------
  dim3 g1(cdiv(N, 64), CH1 / 64);
  k_gemm_f32<64, 64, 16><<<g1, blk, 0, stream>>>(x, W1, bufA, N, CH1, CH1);
  k_aggregate<CH1, true><<<cdiv(N, 4), blk, 0, stream>>>(rowstart, csr, dinv, bufA, b1, bufB, N);

  // --- layer 2: h2 = f1@W2 ; fused aggregate+bias -> out ------------------
  dim3 g2(cdiv(N, 64), CH2 / 64);
  k_gemm_f32<64, 64, 16><<<g2, blk, 0, stream>>>(bufB, W2, bufA, N, CH2, CH1);
  k_aggregate<CH2, false><<<cdiv(N, 4), blk, 0, stream>>>(rowstart, csr, dinv, bufA, b2, out, N);
}

// Round 5
// 278.059 us; speedup vs baseline: 15.4180x; 1.5542x over previous
//
#include <hip/hip_runtime.h>
#include <cstdint>
#include <cstddef>

// ---------------------------------------------------------------------------
// GCN encoder:
//   out[v] = dinv[v] * sum_{e:dst=v} dinv[src]*h[src] + dinv[v]^2*h[v] + b
// Pipeline: CSR build -> split-bf16 MFMA GEMM (hi/lo, 3 passes ~ fp32 acc)
//           -> bf16 gather-aggregate (fp32 accum) fused with bias/ReLU.
// ---------------------------------------------------------------------------

static constexpr int CH1 = 256;
static constexpr int CH2 = 128;

typedef __attribute__((ext_vector_type(8))) short bf16x8;
typedef __attribute__((ext_vector_type(4))) float f32x4;
typedef __attribute__((ext_vector_type(4))) unsigned short u16x4;

__device__ inline unsigned short f2bf(float f) {  // round-to-nearest-even
  unsigned u = __builtin_bit_cast(unsigned, f);
  return (unsigned short)((u + 0x7fffu + ((u >> 16) & 1u)) >> 16);
}
__device__ inline float bf2f(unsigned short h) {
  return __builtin_bit_cast(float, (unsigned)h << 16);
}
__device__ inline float lo16(unsigned u) { return __builtin_bit_cast(float, u << 16); }
__device__ inline float hi16(unsigned u) { return __builtin_bit_cast(float, u & 0xffff0000u); }

__device__ inline void gload16(const void* g, void* l) {
  __builtin_amdgcn_global_load_lds(
      (const __attribute__((address_space(1))) unsigned int*)g,
      (__attribute__((address_space(3))) unsigned int*)l, 16, 0, 0);
}

// ---------------- preprocessing --------------------------------------------

__global__ void k_set_int(int* p, int v) { *p = v; }

__global__ void k_zero_int(int* __restrict__ p, int n) {
  int i = blockIdx.x * blockDim.x + threadIdx.x;
  if (i < n) p[i] = 0;
}

__global__ void k_detect_i32(const unsigned int* __restrict__ w, int nwords,
                             int* __restrict__ flag) {
  int i = blockIdx.x * blockDim.x + threadIdx.x;
  if (i < nwords && (i & 1) && w[i] != 0u) *flag = 1;
}

// fused convert + degree count (deg must be pre-zeroed)
__global__ void k_cvt_deg(const void* __restrict__ raw, int* __restrict__ e32,
                          int* __restrict__ deg, int E, const int* __restrict__ flag) {
  int i = blockIdx.x * blockDim.x + threadIdx.x;
  if (i >= 2 * E) return;
  int v = (*flag) ? ((const int*)raw)[i] : (int)((const long long*)raw)[i];
  e32[i] = v;
  if (i >= E) atomicAdd(&deg[v], 1);  // dst half
}

__global__ __launch_bounds__(256) void k_chunk_sum(const int* __restrict__ deg,
                                                   int* __restrict__ bsum, int N) {
  __shared__ int sh[256];
  int i = blockIdx.x * 256 + threadIdx.x;
  sh[threadIdx.x] = (i < N) ? deg[i] : 0;
  __syncthreads();
  for (int off = 128; off > 0; off >>= 1) {
    if (threadIdx.x < (unsigned)off) sh[threadIdx.x] += sh[threadIdx.x + off];
    __syncthreads();
  }
  if (threadIdx.x == 0) bsum[blockIdx.x] = sh[0];
}

__global__ __launch_bounds__(256) void k_scan_bsums(int* __restrict__ bsum, int nb) {
  __shared__ int sh[256];
  int t = threadIdx.x;
  int v = (t < nb) ? bsum[t] : 0;
  sh[t] = v;
  __syncthreads();
  for (int off = 1; off < 256; off <<= 1) {
    int add = (t >= off) ? sh[t - off] : 0;
    __syncthreads();
    sh[t] += add;
    __syncthreads();
  }
  if (t < nb) bsum[t] = sh[t] - v;  // exclusive
}

__global__ __launch_bounds__(256) void k_chunk_scan(
    const int* __restrict__ deg, const int* __restrict__ bsum,
    int* __restrict__ rowstart, int* __restrict__ cursor,
    float* __restrict__ dinv, int N, int E) {
  __shared__ int sh[256];
  int t = threadIdx.x;
  int i = blockIdx.x * 256 + t;
  int d = (i < N) ? deg[i] : 0;
  sh[t] = d;
  __syncthreads();
  for (int off = 1; off < 256; off <<= 1) {
    int add = (t >= off) ? sh[t - off] : 0;
    __syncthreads();
    sh[t] += add;
    __syncthreads();
  }
  if (i < N) {
    int rs = bsum[blockIdx.x] + sh[t] - d;
    rowstart[i] = rs;
    cursor[i]   = rs;
    dinv[i] = rsqrtf((float)(d + 1));  // +1: self-loop
  }
  if (i == 0) rowstart[N] = E;
}

__global__ void k_fill(const int* __restrict__ src, const int* __restrict__ dst,
                       int* __restrict__ cursor, int* __restrict__ csr, int E) {
  int e = blockIdx.x * blockDim.x + threadIdx.x;
  if (e < E) {
    int pos = atomicAdd(&cursor[dst[e]], 1);
    csr[pos] = src[e];
  }
}

// ---------------- fp32 -> bf16 hi/lo split ---------------------------------

__global__ void k_split4(const float4* __restrict__ in, u16x4* __restrict__ oh,
                         u16x4* __restrict__ ol, int n4) {
  int i = blockIdx.x * blockDim.x + threadIdx.x;
  if (i >= n4) return;
  float4 v = in[i];
  u16x4 h, l;
  h.x = f2bf(v.x); l.x = f2bf(v.x - bf2f(h.x));
  h.y = f2bf(v.y); l.y = f2bf(v.y - bf2f(h.y));
  h.z = f2bf(v.z); l.z = f2bf(v.z - bf2f(h.z));
  h.w = f2bf(v.w); l.w = f2bf(v.w - bf2f(h.w));
  oh[i] = h; ol[i] = l;
}

// W [K,N] fp32 -> W^T hi/lo bf16 [N,K]
__global__ void k_splitT(const float* __restrict__ W, unsigned short* __restrict__ oh,
                         unsigned short* __restrict__ ol, int K, int N) {
  int idx = blockIdx.x * blockDim.x + threadIdx.x;
  if (idx >= K * N) return;
  int k = idx / N, n = idx - k * N;
  float v = W[idx];
  unsigned short h = f2bf(v);
  oh[(size_t)n * K + k] = h;
  ol[(size_t)n * K + k] = f2bf(v - bf2f(h));
}

// ---------------------------------------------------------------------------
// Split-bf16 MFMA GEMM: C[M,BN] = A[M,K] @ B[K,BN], A as (Ah+Al) bf16 pair
// row-major, B as B^T (Bh+Bl) bf16 [BN,K]. acc += AhBh + AhBl + AlBh (fp32).
// BM=64, BK=32, 256 threads (4 waves), wave w owns cols [w*BN/4, ...).
// LDS double-buffered, staged via global_load_lds(16B) with 16B-slot XOR
// swizzle (slot p holds chunk s = p ^ ((row>>1)&3)) -> 2-way-max ds conflicts.
// ---------------------------------------------------------------------------
template <int BN>
__global__ __launch_bounds__(256) void k_gemm_mfma(
    const unsigned short* __restrict__ Ah, const unsigned short* __restrict__ Al,
    const unsigned short* __restrict__ Bh, const unsigned short* __restrict__ Bl,
    unsigned short* __restrict__ Co, int M, int K) {
  constexpr int BM = 64, BK = 32;
  constexpr int NF = BN / 64;          // B frags per wave (4 or 2)
  constexpr int ASZ = BM * BK;         // ushorts per A half
  constexpr int BSZ = BN * BK;         // ushorts per B half
  __shared__ unsigned short lds[2][2 * ASZ + 2 * BSZ];
  const int t = threadIdx.x;
  const int w = t >> 6, l = t & 63;
  const int m0 = blockIdx.x * BM;
  const int lr = l & 15, lk = l >> 4;

  auto stage = [&](int buf, int k0) {
    unsigned short* base = lds[buf];
    {  // A: 256 slots per half, one per thread; dest byte = t*16 (linear)
      int row = t >> 2, p = t & 3;
      int s = p ^ ((row >> 1) & 3);
      int gm = m0 + row; if (gm >= M) gm = M - 1;
      size_t go = (size_t)gm * K + k0 + s * 8;
      gload16(Ah + go, base + (size_t)row * BK + p * 8);
      gload16(Al + go, base + ASZ + (size_t)row * BK + p * 8);
    }
    for (int i = t; i < BN * 4; i += 256) {  // B: BN*4 slots per half
      int n = i >> 2, p = i & 3;
      int s = p ^ ((n >> 1) & 3);
      size_t go = (size_t)n * K + k0 + s * 8;
      gload16(Bh + go, base + 2 * ASZ + (size_t)n * BK + p * 8);
      gload16(Bl + go, base + 2 * ASZ + BSZ + (size_t)n * BK + p * 8);
    }
  };

  f32x4 acc[4][NF];
#pragma unroll
  for (int a = 0; a < 4; ++a)
#pragma unroll
    for (int b = 0; b < NF; ++b) acc[a][b] = (f32x4){0.f, 0.f, 0.f, 0.f};

  stage(0, 0);
  __syncthreads();
  const int nsteps = K / BK;
  for (int ks = 0; ks < nsteps; ++ks) {
    int cur = ks & 1;
    if (ks + 1 < nsteps) stage(cur ^ 1, (ks + 1) * BK);
    const unsigned short* base = lds[cur];
    bf16x8 ah[4], al[4], bh[NF], bl[NF];
#pragma unroll
    for (int fm = 0; fm < 4; ++fm) {
      int row = fm * 16 + lr;
      int p = lk ^ ((row >> 1) & 3);
      const unsigned short* a = base + row * BK + p * 8;
      ah[fm] = *(const bf16x8*)a;
      al[fm] = *(const bf16x8*)(a + ASZ);
    }
#pragma unroll
    for (int fb = 0; fb < NF; ++fb) {
      int n = w * (BN / 4) + fb * 16 + lr;
      int p = lk ^ ((n >> 1) & 3);
      const unsigned short* b = base + 2 * ASZ + n * BK + p * 8;
      bh[fb] = *(const bf16x8*)b;
      bl[fb] = *(const bf16x8*)(b + BSZ);
    }
#pragma unroll
    for (int fm = 0; fm < 4; ++fm)
#pragma unroll
      for (int fb = 0; fb < NF; ++fb) {
        acc[fm][fb] = __builtin_amdgcn_mfma_f32_16x16x32_bf16(ah[fm], bh[fb], acc[fm][fb], 0, 0, 0);
        acc[fm][fb] = __builtin_amdgcn_mfma_f32_16x16x32_bf16(ah[fm], bl[fb], acc[fm][fb], 0, 0, 0);
        acc[fm][fb] = __builtin_amdgcn_mfma_f32_16x16x32_bf16(al[fm], bh[fb], acc[fm][fb], 0, 0, 0);
      }
    __syncthreads();
  }
  // epilogue: C/D layout col=lane&15, row=(lane>>4)*4+reg -> store bf16
#pragma unroll
  for (int fm = 0; fm < 4; ++fm)
#pragma unroll
    for (int r = 0; r < 4; ++r) {
      int row = m0 + fm * 16 + lk * 4 + r;
      if (row < M) {
#pragma unroll
        for (int fb = 0; fb < NF; ++fb) {
          int col = w * (BN / 4) + fb * 16 + lr;
          Co[(size_t)row * BN + col] = f2bf(acc[fm][fb][r]);
        }
      }
    }
}

// ---------------------------------------------------------------------------
// bf16 gather-aggregate, fp32 accum. One 64-lane wave per node.
// MODE 0: out fp32 = dv*acc + dv^2*h[v] + bias          (layer 2)
// MODE 1: relu(...) then split into bf16 hi/lo pair     (layer 1)
// ---------------------------------------------------------------------------
template <int C, int MODE>
__global__ __launch_bounds__(256) void k_agg_bf(
    const int* __restrict__ rowstart, const int* __restrict__ csr,
    const float* __restrict__ dinv, const unsigned short* __restrict__ h,
    const float* __restrict__ bias, float* __restrict__ out,
    unsigned short* __restrict__ oh, unsigned short* __restrict__ ol, int N) {
  constexpr int V = C / 64;  // channels per lane: 4 (C=256) or 2 (C=128)
  static_assert(V == 2 || V == 4, "");
  int wv = blockIdx.x * 4 + (threadIdx.x >> 6);
  if (wv >= N) return;
  int lane = threadIdx.x & 63;
  int beg = rowstart[wv], end = rowstart[wv + 1];
  float acc[V] = {};
  int j = beg;
  if constexpr (V == 4) {
    const unsigned c8 = lane * 4;  // ushort offset; uint2 load (8B)
    for (; j + 4 <= end; j += 4) {
      int s0 = csr[j], s1 = csr[j + 1], s2 = csr[j + 2], s3 = csr[j + 3];
      float w0 = dinv[s0], w1 = dinv[s1], w2 = dinv[s2], w3 = dinv[s3];
      uint2 a0 = *(const uint2*)(h + (size_t)s0 * C + c8);
      uint2 a1 = *(const uint2*)(h + (size_t)s1 * C + c8);
      uint2 a2 = *(const uint2*)(h + (size_t)s2 * C + c8);
      uint2 a3 = *(const uint2*)(h + (size_t)s3 * C + c8);
      acc[0] += w0 * lo16(a0.x) + w1 * lo16(a1.x) + w2 * lo16(a2.x) + w3 * lo16(a3.x);
      acc[1] += w0 * hi16(a0.x) + w1 * hi16(a1.x) + w2 * hi16(a2.x) + w3 * hi16(a3.x);
      acc[2] += w0 * lo16(a0.y) + w1 * lo16(a1.y) + w2 * lo16(a2.y) + w3 * lo16(a3.y);
      acc[3] += w0 * hi16(a0.y) + w1 * hi16(a1.y) + w2 * hi16(a2.y) + w3 * hi16(a3.y);
    }
    for (; j < end; ++j) {
      int s = csr[j];
      float ws = dinv[s];
      uint2 a = *(const uint2*)(h + (size_t)s * C + c8);
      acc[0] += ws * lo16(a.x); acc[1] += ws * hi16(a.x);
      acc[2] += ws * lo16(a.y); acc[3] += ws * hi16(a.y);
    }
    float dv = dinv[wv], sw = dv * dv;
    uint2 hh = *(const uint2*)(h + (size_t)wv * C + c8);
    float4 bb = *(const float4*)(bias + lane * 4);
    float o0 = dv * acc[0] + sw * lo16(hh.x) + bb.x;
    float o1 = dv * acc[1] + sw * hi16(hh.x) + bb.y;
    float o2 = dv * acc[2] + sw * lo16(hh.y) + bb.z;
    float o3 = dv * acc[3] + sw * hi16(hh.y) + bb.w;
    if constexpr (MODE == 1) {
      o0 = fmaxf(o0, 0.f); o1 = fmaxf(o1, 0.f);
      o2 = fmaxf(o2, 0.f); o3 = fmaxf(o3, 0.f);
      u16x4 vh, vl;
      vh.x = f2bf(o0); vl.x = f2bf(o0 - bf2f(vh.x));
      vh.y = f2bf(o1); vl.y = f2bf(o1 - bf2f(vh.y));
      vh.z = f2bf(o2); vl.z = f2bf(o2 - bf2f(vh.z));
      vh.w = f2bf(o3); vl.w = f2bf(o3 - bf2f(vh.w));
      *(u16x4*)(oh + (size_t)wv * C + c8) = vh;
      *(u16x4*)(ol + (size_t)wv * C + c8) = vl;
    } else {
      *(float4*)(out + (size_t)wv * C + lane * 4) = make_float4(o0, o1, o2, o3);
    }
  } else {
    const unsigned c4 = lane * 2;  // ushort offset; uint load (4B)
    for (; j + 4 <= end; j += 4) {
      int s0 = csr[j], s1 = csr[j + 1], s2 = csr[j + 2], s3 = csr[j + 3];
      float w0 = dinv[s0], w1 = dinv[s1], w2 = dinv[s2], w3 = dinv[s3];
      unsigned a0 = *(const unsigned*)(h + (size_t)s0 * C + c4);
      unsigned a1 = *(const unsigned*)(h + (size_t)s1 * C + c4);
      unsigned a2 = *(const unsigned*)(h + (size_t)s2 * C + c4);
      unsigned a3 = *(const unsigned*)(h + (size_t)s3 * C + c4);
      acc[0] += w0 * lo16(a0) + w1 * lo16(a1) + w2 * lo16(a2) + w3 * lo16(a3);
      acc[1] += w0 * hi16(a0) + w1 * hi16(a1) + w2 * hi16(a2) + w3 * hi16(a3);
    }
    for (; j < end; ++j) {
      int s = csr[j];
      float ws = dinv[s];
      unsigned a = *(const unsigned*)(h + (size_t)s * C + c4);
      acc[0] += ws * lo16(a); acc[1] += ws * hi16(a);
    }
    float dv = dinv[wv], sw = dv * dv;
    unsigned hh = *(const unsigned*)(h + (size_t)wv * C + c4);
    float2 bb = *(const float2*)(bias + lane * 2);
    float o0 = dv * acc[0] + sw * lo16(hh) + bb.x;
    float o1 = dv * acc[1] + sw * hi16(hh) + bb.y;
    *(float2*)(out + (size_t)wv * C + lane * 2) = make_float2(o0, o1);
  }
}

// ---------------------------------------------------------------------------

extern "C" void kernel_launch(void* const* d_in, const int* in_sizes, int n_in,
                              void* d_out, int out_size, void* d_ws, size_t ws_size,
                              hipStream_t stream) {
  const float* x  = (const float*)d_in[0];
  const void*  ei = d_in[1];
  const float* W1 = (const float*)d_in[2];
  const float* b1 = (const float*)d_in[3];
  const float* W2 = (const float*)d_in[4];
  const float* b2 = (const float*)d_in[5];
  float* out = (float*)d_out;

  const int N = in_sizes[0] / CH1;  // 50000
  const int E = in_sizes[1] / 2;    // 800000

  char* w = (char*)d_ws;
  size_t off = 0;
  auto alloc = [&](size_t bytes) -> void* {
    void* p = w + off;
    off += (bytes + 255) & ~(size_t)255;
    return p;
  };
  int*   deg      = (int*)alloc((size_t)N * 4);
  int*   flag     = (int*)alloc(256);
  int*   e32      = (int*)alloc((size_t)2 * E * 4);
  int*   rowstart = (int*)alloc((size_t)(N + 1) * 4);
  int*   cursor   = (int*)alloc((size_t)N * 4);
  int*   bsum     = (int*)alloc(256 * 4);
  int*   csr      = (int*)alloc((size_t)E * 4);
  float* dinv     = (float*)alloc((size_t)N * 4);
  unsigned short* xh  = (unsigned short*)alloc((size_t)N * CH1 * 2);  // also f1_hi
  unsigned short* xl  = (unsigned short*)alloc((size_t)N * CH1 * 2);  // also f1_lo
  unsigned short* h1  = (unsigned short*)alloc((size_t)N * CH1 * 2);
  unsigned short* h2  = (unsigned short*)alloc((size_t)N * CH2 * 2);
  unsigned short* w1th = (unsigned short*)alloc((size_t)CH1 * CH1 * 2);
  unsigned short* w1tl = (unsigned short*)alloc((size_t)CH1 * CH1 * 2);
  unsigned short* w2th = (unsigned short*)alloc((size_t)CH1 * CH2 * 2);
  unsigned short* w2tl = (unsigned short*)alloc((size_t)CH1 * CH2 * 2);

  const int* srcI = e32;
  const int* dstI = e32 + E;

  dim3 blk(256);
  auto cdiv = [](long long a, long long b) { return (int)((a + b - 1) / b); };
  const int nchunks = cdiv(N, 256);

  // --- CSR build ----------------------------------------------------------
  k_set_int<<<1, 1, 0, stream>>>(flag, 0);
  k_detect_i32<<<cdiv(2LL * E, 256), blk, 0, stream>>>((const unsigned int*)ei, 2 * E, flag);
  k_zero_int<<<cdiv(N, 256), blk, 0, stream>>>(deg, N);
  k_cvt_deg<<<cdiv(2LL * E, 256), blk, 0, stream>>>(ei, e32, deg, E, flag);
  k_chunk_sum<<<nchunks, blk, 0, stream>>>(deg, bsum, N);
  k_scan_bsums<<<1, blk, 0, stream>>>(bsum, nchunks);
  k_chunk_scan<<<nchunks, blk, 0, stream>>>(deg, bsum, rowstart, cursor, dinv, N, E);
  k_fill<<<cdiv(E, 256), blk, 0, stream>>>(srcI, dstI, cursor, csr, E);

  // --- input splits -------------------------------------------------------
  k_split4<<<cdiv((long long)N * CH1 / 4, 256), blk, 0, stream>>>(
      (const float4*)x, (u16x4*)xh, (u16x4*)xl, N * CH1 / 4);
  k_splitT<<<cdiv(CH1 * CH1, 256), blk, 0, stream>>>(W1, w1th, w1tl, CH1, CH1);
  k_splitT<<<cdiv(CH1 * CH2, 256), blk, 0, stream>>>(W2, w2th, w2tl, CH1, CH2);

  // --- layer 1 ------------------------------------------------------------
  k_gemm_mfma<CH1><<<cdiv(N, 64), blk, 0, stream>>>(xh, xl, w1th, w1tl, h1, N, CH1);
  k_agg_bf<CH1, 1><<<cdiv(N, 4), blk, 0, stream>>>(rowstart, csr, dinv, h1, b1,
                                                   nullptr, xh, xl, N);  // f1 -> xh/xl
  // --- layer 2 ------------------------------------------------------------
  k_gemm_mfma<CH2><<<cdiv(N, 64), blk, 0, stream>>>(xh, xl, w2th, w2tl, h2, N, CH1);
  k_agg_bf<CH2, 0><<<cdiv(N, 4), blk, 0, stream>>>(rowstart, csr, dinv, h2, b2,
                                                   out, nullptr, nullptr, N);
}